// Round 11
// baseline (135.306 us; speedup 1.0000x reference)
//
#include <hip/hip_runtime.h>
#include <hip/hip_bf16.h>

// Deformable conv via FUSED implicit GEMM on MFMA.
// B=8, C=256, H=W=64, O=256, K=3.
// R11: kill the scattered-gather transaction wall (measured 6.2cyc/segment x
//   36.9K segments/CU = the whole kernel). xT becomes chunk-planar
//   [b][cc][pos][32ch]; dcn_fused loops cc-outer x tap-inner; per cc a 12-row
//   x-window (48KB) is staged ONCE coalesced into LDS and all corner gathers
//   become ds_read_b128. Out-of-window corners (P~1e-13) take a global
//   fallback branch. Simple R5-style 2-phase K-loop (schedules proven neutral).

#define HW 64
#define CCH 256
#define OCH 256
#define BB 8
#define KDIM 2304  // 9 * 256, order kk*256 + c

typedef __attribute__((ext_vector_type(8))) short bf16x8;
typedef __attribute__((ext_vector_type(8))) unsigned short u16x8;
typedef __attribute__((ext_vector_type(4))) float f32x4;
typedef __attribute__((ext_vector_type(2))) float f32x2;
typedef __attribute__((ext_vector_type(4))) unsigned short u16x4;
typedef __attribute__((ext_vector_type(4))) unsigned int u32x4;

static __device__ inline unsigned short f2bf(float f) {
  unsigned u = __builtin_bit_cast(unsigned, f);
  u += 0x7FFFu + ((u >> 16) & 1u);  // RNE
  return (unsigned short)(u >> 16);
}
static __device__ inline float bf2f(unsigned short s) {
  return __builtin_bit_cast(float, (unsigned)s << 16);
}
static __device__ inline unsigned cvt_pk_bf16(float lo, float hi) {
  unsigned r;
  asm("v_cvt_pk_bf16_f32 %0, %1, %2" : "=v"(r) : "v"(lo), "v"(hi));
  return r;
}

#define GLL16(gsrc, ldst)                                                      \
  __builtin_amdgcn_global_load_lds(                                           \
      (const __attribute__((address_space(1))) void*)(gsrc),                  \
      (__attribute__((address_space(3))) void*)(ldst), 16, 0, 0)

static __device__ inline int xcd_swz256(int bid) {
  return (bid & 7) * 32 + (bid >> 3);
}

// ---------------- prep (unchanged) ----------------
__global__ __launch_bounds__(256) void prep(const float* __restrict__ w_dcn,
                                            const float* __restrict__ w_off,
                                            unsigned short* __restrict__ W2,
                                            unsigned short* __restrict__ Wop,
                                            unsigned short* __restrict__ zp) {
  int i = blockIdx.x * 256 + threadIdx.x;
  if (i < 9 * 256 * 256) {
    int o = i / KDIM;
    int r = i - o * KDIM;
    int kk = r >> 8, c = r & 255;
    W2[i] = f2bf(w_dcn[((o << 8) + c) * 9 + kk]);
  }
  if (i < 32 * KDIM) {
    int n = i / KDIM;
    int r = i - n * KDIM;
    int kk = r >> 8, c = r & 255;
    Wop[i] = (n < 18) ? f2bf(w_off[((n << 8) + c) * 9 + kk]) : (unsigned short)0;
  }
  if (i < 512) zp[i] = 0;
}

// ---------------- xpose: NCHW f32 -> chunk-planar bf16 ----------------
// xTc[b][cc][pos][ci]: addr = b*2^20 + cc*131072 + pos*32 + ci  (shorts)
__global__ __launch_bounds__(256) void xpose(const float* __restrict__ x,
                                             unsigned short* __restrict__ xTbf) {
  __shared__ float t[64][65];
  const int tid = threadIdx.x;
  const int bid = blockIdx.x;
  const int ct = bid & 3;
  const int pt = (bid >> 2) & 63;
  const int b = bid >> 8;
#pragma unroll
  for (int i = 0; i < 16; ++i) {
    int cl = i * 4 + (tid >> 6);
    int p = tid & 63;
    t[cl][p] = x[(((b << 8) + ct * 64 + cl) << 12) + pt * 64 + p];
  }
  __syncthreads();
#pragma unroll
  for (int i = 0; i < 4; ++i) {
    int pl = i * 16 + (tid >> 4);
    int c4 = (tid & 15) * 4;
    int c = ct * 64 + c4;
    int pos = pt * 64 + pl;
    u16x4 v;
    v[0] = f2bf(t[c4][pl]);
    v[1] = f2bf(t[c4 + 1][pl]);
    v[2] = f2bf(t[c4 + 2][pl]);
    v[3] = f2bf(t[c4 + 3][pl]);
    *(u16x4*)(xTbf + ((size_t)b << 20) + (c >> 5) * 131072 + pos * 32 +
              (c & 31)) = v;
  }
}

// ---------------- offset_gemm (A-src updated to chunk-planar) ----------------
__global__ __launch_bounds__(256) void offset_gemm(
    const unsigned short* __restrict__ xTbf, const unsigned short* __restrict__ Wop,
    const unsigned short* __restrict__ zp, const float* __restrict__ b_off,
    float* __restrict__ off_buf) {
  __shared__ short ldsA[2][128 * 32];
  __shared__ short ldsB[2][32 * 32];
  const int tid = threadIdx.x;
  const int lane = tid & 63;
  const int wid = __builtin_amdgcn_readfirstlane(tid >> 6);
  const int m0 = xcd_swz256(blockIdx.x) * 128;
  const int b = m0 >> 12;
  const unsigned short* xb = xTbf + ((size_t)b << 20);

  int hA[2], wA[2], scA[2];
#pragma unroll
  for (int g = 0; g < 2; ++g) {
    int r = wid * 32 + g * 16 + (lane >> 2);
    int pos = (m0 & 4095) + r;
    hA[g] = pos >> 6;
    wA[g] = pos & 63;
    scA[g] = ((lane & 3) ^ ((r >> 1) & 3)) * 8;
  }
  const int rB = wid * 16 + (lane >> 2);
  const unsigned short* srcB =
      Wop + (size_t)rB * KDIM + ((lane & 3) ^ ((rB >> 1) & 3)) * 8;

  const int l15 = lane & 15, l4 = lane >> 4;
  int offA[2], offB[2];
#pragma unroll
  for (int f = 0; f < 2; ++f) {
    int rA = wid * 32 + f * 16 + l15;
    offA[f] = rA * 32 + ((l4 ^ ((rA >> 1) & 3)) << 3);
    int rb = f * 16 + l15;
    offB[f] = rb * 32 + ((l4 ^ ((rb >> 1) & 3)) << 3);
  }

  const f32x4 z = {0.f, 0.f, 0.f, 0.f};
  f32x4 acc[2][2];
#pragma unroll
  for (int i = 0; i < 2; ++i)
#pragma unroll
    for (int j = 0; j < 2; ++j) acc[i][j] = z;

  auto stage = [&](int buf, int t) {
    const int kk = t >> 3;
    const int cc = t & 7;
    const int dy = kk / 3 - 1, dx = kk - (kk / 3) * 3 - 1;
#pragma unroll
    for (int g = 0; g < 2; ++g) {
      const int y = hA[g] + dy, xx = wA[g] + dx;
      const bool valid = ((unsigned)y < 64u) && ((unsigned)xx < 64u);
      const unsigned short* src =
          valid ? xb + cc * 131072 + ((y << 6) + xx) * 32 + scA[g]
                : zp + scA[g];
      GLL16(src, &ldsA[buf][((wid * 2 + g) * 64 + lane) * 8]);
    }
    if (wid < 2) GLL16(srcB + t * 32, &ldsB[buf][(wid * 64 + lane) * 8]);
  };

  stage(0, 0);
  __syncthreads();

  for (int t = 0; t < 72; ++t) {
    const int buf = t & 1;
    if (t < 71) stage(buf ^ 1, t + 1);
    bf16x8 af[2], bfr[2];
#pragma unroll
    for (int f = 0; f < 2; ++f) af[f] = *(const bf16x8*)&ldsA[buf][offA[f]];
#pragma unroll
    for (int f = 0; f < 2; ++f) bfr[f] = *(const bf16x8*)&ldsB[buf][offB[f]];
#pragma unroll
    for (int i = 0; i < 2; ++i)
#pragma unroll
      for (int j = 0; j < 2; ++j)
        acc[i][j] = __builtin_amdgcn_mfma_f32_16x16x32_bf16(af[i], bfr[j],
                                                            acc[i][j], 0, 0, 0);
    __syncthreads();
  }

#pragma unroll
  for (int j = 0; j < 2; ++j) {
    const int col = j * 16 + l15;
    if (col < 18) {
      const float bias = b_off[col];
#pragma unroll
      for (int i = 0; i < 2; ++i)
#pragma unroll
        for (int r = 0; r < 4; ++r) {
          const int m = m0 + wid * 32 + i * 16 + l4 * 4 + r;
          off_buf[(size_t)m * 18 + col] = acc[i][j][r] + bias;
        }
    }
  }
}

// ---------------- dcn_fused (R11: LDS x-window) ----------------
// BM=128, BN=256, BK=32. K-order: cc-outer (8 chunks of 32ch) x tap-inner (9).
// Per cc: stage 12-row x 64-x x 32-ch window (48KB) coalesced; 9 tap-steps
// gather corners from LDS. 512 threads; thread samples row r=tid>>2, 8ch q=tid&3.
__global__ __launch_bounds__(512, 2) void dcn_fused(
    const unsigned short* __restrict__ xTbf, const float* __restrict__ off_buf,
    const unsigned short* __restrict__ W2, float* __restrict__ out) {
  __shared__ f32x2 slyx[128][9];      // (ly, lx)                      9.2KB
  __shared__ u16x4 spos[128][9];      // pos12 | inwin<<14(e0) | v<<15 9.2KB
  __shared__ short win[12 * 64 * 32]; // x-window for current cc       48KB
  __shared__ short ldsA[2][128 * 32]; //                               16KB
  __shared__ short ldsB[2][256 * 32]; //                               32KB

  const int tid = threadIdx.x;
  const int lane = tid & 63;
  const int wid = __builtin_amdgcn_readfirstlane(tid >> 6);
  const int m0 = xcd_swz256(blockIdx.x) * 128;
  const int b = m0 >> 12;
  const unsigned short* xb = xTbf + ((size_t)b << 20);
  const int h0 = (m0 & 4095) >> 6;
  const int ys = max(0, h0 - 5);  // window rows [ys, ys+11] (clamped staging)

  // ---- window staging (coalesced GLL16; 6 per thread) ----
  auto stage_window = [&](int cc) {
    const unsigned short* xbc = xb + cc * 131072;
#pragma unroll
    for (int g = 0; g < 6; ++g) {
      const int o = g * 8192 + tid * 16;  // byte offset in win
      const int rel = o >> 12;
      const int xw = (o >> 6) & 63;
      const int cs = (o & 63) >> 1;  // short offset within 32ch
      const int ysrc = min(63, ys + rel);
      GLL16(xbc + ((ysrc << 6) + xw) * 32 + cs, &win[o >> 1]);
    }
  };

  // ---- phase 0: window(0) staged early; params computed meanwhile ----
  stage_window(0);
  for (int idx = tid; idx < 128 * 9; idx += 512) {
    const int r = idx / 9, k = idx - (idx / 9) * 9;
    const int ky = k / 3, kx = k - ky * 3;
    const int pos = (m0 & 4095) + r;
    const int h = pos >> 6, w = pos & 63;
    const float offy = off_buf[(size_t)(m0 + r) * 18 + 2 * k];
    const float offx = off_buf[(size_t)(m0 + r) * 18 + 2 * k + 1];
    const float sy = offy + (float)(h - 1 + ky);
    const float sx = offx + (float)(w - 1 + kx);
    const float y0f = floorf(sy), x0f = floorf(sx);
    const int y0 = (int)y0f, x0 = (int)x0f;
    const int y1 = y0 + 1, x1 = x0 + 1;
    const unsigned vy0 = ((unsigned)y0 < 64u), vy1 = ((unsigned)y1 < 64u);
    const unsigned vx0 = ((unsigned)x0 < 64u), vx1 = ((unsigned)x1 < 64u);
    const int y0c = min(max(y0, 0), HW - 1), y1c = min(max(y1, 0), HW - 1);
    const int x0c = min(max(x0, 0), HW - 1), x1c = min(max(x1, 0), HW - 1);
    const unsigned inwin = (y0c >= ys) & (y1c <= ys + 11);
    f32x2 lyx;
    lyx[0] = sy - y0f;
    lyx[1] = sx - x0f;
    u16x4 pp;
    pp[0] = (unsigned short)(((y0c << 6) + x0c) | (inwin << 14) |
                             ((vy0 & vx0) << 15));
    pp[1] = (unsigned short)(((y0c << 6) + x1c) | ((vy0 & vx1) << 15));
    pp[2] = (unsigned short)(((y1c << 6) + x0c) | ((vy1 & vx0) << 15));
    pp[3] = (unsigned short)(((y1c << 6) + x1c) | ((vy1 & vx1) << 15));
    slyx[r][k] = lyx;
    spos[r][k] = pp;
  }

  // ---- roles ----
  const int r = tid >> 2, q = tid & 3;  // sampling: row, 8-ch quarter of 32
  const int q8 = q * 8;
  const int dstA = r * 32 + ((q ^ ((r >> 1) & 3)) << 3);
  // B staging: 2 GLL16/thread, dst lane-linear, src chunk pre-swizzled.
  const unsigned short* srcBp[2];
  int dstB[2];
#pragma unroll
  for (int g = 0; g < 2; ++g) {
    const int idx = g * 512 + tid;
    const int row = idx >> 2, c = idx & 3;
    srcBp[g] = W2 + (size_t)row * KDIM + ((c ^ ((row >> 1) & 3)) << 3);
    dstB[g] = idx * 8;
  }

  const int l15 = lane & 15, l4 = lane >> 4;
  const int wm = wid & 1, wn = wid >> 1;
  int offA[4], offB[4];
#pragma unroll
  for (int f = 0; f < 4; ++f) {
    const int rA = wm * 64 + f * 16 + l15;
    offA[f] = rA * 32 + ((l4 ^ ((rA >> 1) & 3)) << 3);
    const int rB = wn * 64 + f * 16 + l15;
    offB[f] = rB * 32 + ((l4 ^ ((rB >> 1) & 3)) << 3);
  }

  const f32x4 z = {0.f, 0.f, 0.f, 0.f};
  f32x4 acc[4][4];
#pragma unroll
  for (int i = 0; i < 4; ++i)
#pragma unroll
    for (int j = 0; j < 4; ++j) acc[i][j] = z;

  // produce A-tile fragment for (tap, cc) into ldsA[buf].
  auto produce = [&](int buf, int tap, int cc) {
    const f32x2 lyx = slyx[r][tap];
    const u16x4 pp = spos[r][tap];
    const float ly = lyx[0], lx = lyx[1];
    const float w0 = (1.f - ly) * (1.f - lx) * (float)(pp[0] >> 15);
    const float w1 = (1.f - ly) * lx * (float)(pp[1] >> 15);
    const float w2 = ly * (1.f - lx) * (float)(pp[2] >> 15);
    const float w3 = ly * lx * (float)(pp[3] >> 15);
    int po[4];
#pragma unroll
    for (int e = 0; e < 4; ++e) po[e] = pp[e] & 0x0FFF;
    u16x8 c[4];
    if (__builtin_expect((pp[0] >> 14) & 1, 1)) {
#pragma unroll
      for (int e = 0; e < 4; ++e)
        c[e] = *(const u16x8*)&win[((po[e] >> 6) - ys) * 2048 +
                                   (po[e] & 63) * 32 + q8];
    } else {  // out-of-window fallback (P ~ 1e-13): global gather
      const unsigned short* xbc = xb + cc * 131072;
#pragma unroll
      for (int e = 0; e < 4; ++e)
        c[e] = *(const u16x8*)(xbc + po[e] * 32 + q8);
    }
    u32x4 wds;
#pragma unroll
    for (int e = 0; e < 4; ++e) {
      const float f0 = w0 * bf2f(c[0][2 * e]) + w1 * bf2f(c[1][2 * e]) +
                       w2 * bf2f(c[2][2 * e]) + w3 * bf2f(c[3][2 * e]);
      const float f1 = w0 * bf2f(c[0][2 * e + 1]) + w1 * bf2f(c[1][2 * e + 1]) +
                       w2 * bf2f(c[2][2 * e + 1]) + w3 * bf2f(c[3][2 * e + 1]);
      wds[e] = cvt_pk_bf16(f0, f1);
    }
    *(u32x4*)&ldsA[buf][dstA] = wds;
  };

  // ---- prologue: B(0); drain window+params; A(0) ----
  GLL16(srcBp[0], &ldsB[0][dstB[0]]);
  GLL16(srcBp[1], &ldsB[0][dstB[1]]);
  asm volatile("s_waitcnt vmcnt(0) lgkmcnt(0)" ::: "memory");
  __builtin_amdgcn_s_barrier();
  produce(0, 0, 0);
  __syncthreads();

  // ---- main loop: 72 steps = 8 cc x 9 taps ----
  int t = 0;
  for (int cc = 0; cc < 8; ++cc) {
    for (int tap = 0; tap < 9; ++tap, ++t) {
      const int buf = t & 1;
      const bool last = (t == 71);
      if (!last) {
        const int tapn = (tap == 8) ? 0 : tap + 1;
        const int ccn = (tap == 8) ? cc + 1 : cc;
        const int koff = tapn * 256 + ccn * 32;
        GLL16(srcBp[0] + koff, &ldsB[buf ^ 1][dstB[0]]);
        GLL16(srcBp[1] + koff, &ldsB[buf ^ 1][dstB[1]]);
        if (tap != 8) produce(buf ^ 1, tapn, cc);
      }
      bf16x8 af[4], bfr[4];
#pragma unroll
      for (int f = 0; f < 4; ++f) {
        af[f] = *(const bf16x8*)&ldsA[buf][offA[f]];
        bfr[f] = *(const bf16x8*)&ldsB[buf][offB[f]];
      }
      __builtin_amdgcn_s_setprio(1);
#pragma unroll
      for (int i = 0; i < 4; ++i)
#pragma unroll
        for (int j = 0; j < 4; ++j)
          acc[i][j] = __builtin_amdgcn_mfma_f32_16x16x32_bf16(af[i], bfr[j],
                                                              acc[i][j], 0, 0, 0);
      __builtin_amdgcn_s_setprio(0);
      if (!last && tap == 8) {
        // chunk boundary: window[cc] is dead (last read was step t-1).
        stage_window(cc + 1);
        asm volatile("s_waitcnt vmcnt(0) lgkmcnt(0)" ::: "memory");
        __builtin_amdgcn_s_barrier();
        produce(buf ^ 1, 0, cc + 1);
        __syncthreads();
      } else {
        __syncthreads();
      }
    }
  }

  // ---- epilogue ----
#pragma unroll
  for (int i = 0; i < 4; ++i) {
    const int m = m0 + wm * 64 + i * 16 + l4 * 4;
    const int bb = m >> 12;
    const int pos = m & 4095;
#pragma unroll
    for (int j = 0; j < 4; ++j) {
      const int o = wn * 64 + j * 16 + l15;
      *(f32x4*)(out + (((size_t)bb * OCH + o) << 12) + pos) = acc[i][j];
    }
  }
}

extern "C" void kernel_launch(void* const* d_in, const int* in_sizes, int n_in,
                              void* d_out, int out_size, void* d_ws,
                              size_t ws_size, hipStream_t stream) {
  const float* x = (const float*)d_in[0];
  const float* w_off = (const float*)d_in[1];
  const float* b_off = (const float*)d_in[2];
  const float* w_dcn = (const float*)d_in[3];
  float* out = (float*)d_out;

  char* ws = (char*)d_ws;
  float* off_buf = (float*)(ws);                            //  2,359,296 B
  unsigned short* Wop = (unsigned short*)(ws + 2359296);    //    147,456 B
  unsigned short* zp = (unsigned short*)(ws + 2506752);     //      1,024 B
  unsigned short* W2 = (unsigned short*)(ws + 2507776);     //  1,179,648 B
  unsigned short* xTbf = (unsigned short*)(ws + 3687424);   // 16,777,216 B
  // total 20,464,640 B

  prep<<<2304, 256, 0, stream>>>(w_dcn, w_off, W2, Wop, zp);
  xpose<<<2048, 256, 0, stream>>>(x, xTbf);
  offset_gemm<<<256, 256, 0, stream>>>(xTbf, Wop, zp, b_off, off_buf);
  dcn_fused<<<256, 512, 0, stream>>>(xTbf, off_buf, W2, out);
}

// Round 13
// 119.808 us; speedup vs baseline: 1.1294x; 1.1294x over previous
//
#include <hip/hip_runtime.h>
#include <hip/hip_bf16.h>

// Deformable conv via FUSED implicit GEMM on MFMA.
// B=8, C=256, H=W=64, O=256, K=3.
// R13: revert to proven bf16 pipeline (R9 dcn_fused verbatim; R12's all-f16
//   rewrite failed correctness — unexplained, suspect packed-f16 lowering).
//   Safe harvests: prep+xpose merged into one launch; offset_gemm
//   re-partitioned to 512 threads / 8 waves (same grid, same addresses).

#define HW 64
#define CCH 256
#define OCH 256
#define BB 8
#define KDIM 2304  // 9 * 256, order kk*256 + c

typedef __attribute__((ext_vector_type(8))) short bf16x8;
typedef __attribute__((ext_vector_type(8))) unsigned short u16x8;
typedef __attribute__((ext_vector_type(4))) float f32x4;
typedef __attribute__((ext_vector_type(2))) float f32x2;
typedef __attribute__((ext_vector_type(4))) unsigned short u16x4;
typedef __attribute__((ext_vector_type(4))) unsigned int u32x4;

static __device__ inline unsigned short f2bf(float f) {
  unsigned u = __builtin_bit_cast(unsigned, f);
  u += 0x7FFFu + ((u >> 16) & 1u);  // RNE
  return (unsigned short)(u >> 16);
}
static __device__ inline float bf2f(unsigned short s) {
  return __builtin_bit_cast(float, (unsigned)s << 16);
}
static __device__ inline unsigned cvt_pk_bf16(float lo, float hi) {
  unsigned r;
  asm("v_cvt_pk_bf16_f32 %0, %1, %2" : "=v"(r) : "v"(lo), "v"(hi));
  return r;
}

#define GLL16(gsrc, ldst)                                                      \
  __builtin_amdgcn_global_load_lds(                                           \
      (const __attribute__((address_space(1))) void*)(gsrc),                  \
      (__attribute__((address_space(3))) void*)(ldst), 16, 0, 0)

static __device__ inline int xcd_swz256(int bid) {
  return (bid & 7) * 32 + (bid >> 3);
}

// ---------------- prep_xpose: merged (independent workloads) ----------------
// blocks [0,2048):  xpose  x f32 NCHW -> xTbf bf16 NHWC
// blocks [2048,4352): prep  weights -> bf16 (W2, Wop) + zero page
__global__ __launch_bounds__(256) void prep_xpose(
    const float* __restrict__ x, const float* __restrict__ w_dcn,
    const float* __restrict__ w_off, unsigned short* __restrict__ xTbf,
    unsigned short* __restrict__ W2, unsigned short* __restrict__ Wop,
    unsigned short* __restrict__ zp) {
  const int tid = threadIdx.x;
  const int bid = blockIdx.x;
  if (bid < 2048) {
    __shared__ float t[64][65];
    const int ct = bid & 3;
    const int pt = (bid >> 2) & 63;
    const int b = bid >> 8;
#pragma unroll
    for (int i = 0; i < 16; ++i) {
      int cl = i * 4 + (tid >> 6);
      int p = tid & 63;
      t[cl][p] = x[(((b << 8) + ct * 64 + cl) << 12) + pt * 64 + p];
    }
    __syncthreads();
#pragma unroll
    for (int i = 0; i < 4; ++i) {
      int pl = i * 16 + (tid >> 4);
      int c4 = (tid & 15) * 4;
      u16x4 v;
      v[0] = f2bf(t[c4][pl]);
      v[1] = f2bf(t[c4 + 1][pl]);
      v[2] = f2bf(t[c4 + 2][pl]);
      v[3] = f2bf(t[c4 + 3][pl]);
      *(u16x4*)(xTbf + (((size_t)((b << 12) + pt * 64 + pl)) << 8) + ct * 64 +
                c4) = v;
    }
  } else {
    int i = (bid - 2048) * 256 + tid;
    if (i < 9 * 256 * 256) {
      int o = i / KDIM;
      int r = i - o * KDIM;
      int kk = r >> 8, c = r & 255;
      W2[i] = f2bf(w_dcn[((o << 8) + c) * 9 + kk]);
    }
    if (i < 32 * KDIM) {
      int n = i / KDIM;
      int r = i - n * KDIM;
      int kk = r >> 8, c = r & 255;
      Wop[i] = (n < 18) ? f2bf(w_off[((n << 8) + c) * 9 + kk]) : (unsigned short)0;
    }
    if (i < 512) zp[i] = 0;
  }
}

// ---------------- offset_gemm (R13: 512 threads, 8 waves, same addresses) ----
// BM=128, BN=32(18), BK=32, grid=256. Wave tile 16x32: wave wid owns rows
// [wid*16, wid*16+16). A staging: thread (r=tid>>2, c=tid&3) -> 1 GLL16,
// dst tid-linear, src chunk pre-swizzled (c ^ ((r>>1)&3)).
__global__ __launch_bounds__(512) void offset_gemm(
    const unsigned short* __restrict__ xTbf, const unsigned short* __restrict__ Wop,
    const unsigned short* __restrict__ zp, const float* __restrict__ b_off,
    float* __restrict__ off_buf) {
  __shared__ short ldsA[2][128 * 32];
  __shared__ short ldsB[2][32 * 32];
  const int tid = threadIdx.x;
  const int lane = tid & 63;
  const int wid = __builtin_amdgcn_readfirstlane(tid >> 6);
  const int m0 = xcd_swz256(blockIdx.x) * 128;
  const int b = m0 >> 12;
  const unsigned short* xb = xTbf + ((size_t)b << 20);

  // A staging: one row/chunk per thread.
  const int rS = tid >> 2;            // row 0..127
  const int cS = tid & 3;             // chunk
  const int posS = (m0 & 4095) + rS;
  const int hS = posS >> 6, wS = posS & 63;
  const int scS = (cS ^ ((rS >> 1) & 3)) * 8;  // pre-swizzled source chunk
  // B staging: threads 0..127 (waves 0,1 -> lane-linear dst within wave).
  const int rB = tid >> 2;            // row 0..31 (tid<128)
  const unsigned short* srcB =
      Wop + (size_t)rB * KDIM + ((tid & 3) ^ ((rB >> 1) & 3)) * 8;

  const int l15 = lane & 15, l4 = lane >> 4;
  const int rA = wid * 16 + l15;
  const int offA = rA * 32 + ((l4 ^ ((rA >> 1) & 3)) << 3);
  int offB[2];
#pragma unroll
  for (int f = 0; f < 2; ++f) {
    const int rb = f * 16 + l15;
    offB[f] = rb * 32 + ((l4 ^ ((rb >> 1) & 3)) << 3);
  }

  const f32x4 z = {0.f, 0.f, 0.f, 0.f};
  f32x4 acc[2];
  acc[0] = z;
  acc[1] = z;

  auto stage = [&](int buf, int t) {
    const int kk = t >> 3;
    const int c0 = (t & 7) * 32;
    const int dy = kk / 3 - 1, dx = kk - (kk / 3) * 3 - 1;
    const int y = hS + dy, xx = wS + dx;
    const bool valid = ((unsigned)y < 64u) && ((unsigned)xx < 64u);
    const unsigned short* src =
        valid ? xb + ((((y << 6) + xx) << 8) + c0 + scS) : zp + scS;
    GLL16(src, &ldsA[buf][tid * 8]);
    if (tid < 128) GLL16(srcB + t * 32, &ldsB[buf][tid * 8]);
  };

  stage(0, 0);
  __syncthreads();

  for (int t = 0; t < 72; ++t) {
    const int buf = t & 1;
    if (t < 71) stage(buf ^ 1, t + 1);
    bf16x8 af, bfr[2];
    af = *(const bf16x8*)&ldsA[buf][offA];
#pragma unroll
    for (int f = 0; f < 2; ++f) bfr[f] = *(const bf16x8*)&ldsB[buf][offB[f]];
#pragma unroll
    for (int j = 0; j < 2; ++j)
      acc[j] = __builtin_amdgcn_mfma_f32_16x16x32_bf16(af, bfr[j], acc[j],
                                                       0, 0, 0);
    __syncthreads();
  }

#pragma unroll
  for (int j = 0; j < 2; ++j) {
    const int col = j * 16 + l15;
    if (col < 18) {
      const float bias = b_off[col];
#pragma unroll
      for (int rr = 0; rr < 4; ++rr) {
        const int m = m0 + wid * 16 + l4 * 4 + rr;
        off_buf[(size_t)m * 18 + col] = acc[j][rr] + bias;
      }
    }
  }
}

// ---------------- dcn_fused (R9 verbatim: bf16, BK=64) ----------------
// BM=128, BN=256, BK=64, 36 K-steps. 512 threads (8 waves), grid=256.
// Sampling role: r=tid>>2 (row), q=tid&3 -> 16 channels of the 64-ch K-tile.
// A LDS [128][64] chunk^=(row&7); B staged via GLL w/ pre-swizzled source.
__global__ __launch_bounds__(512, 2) void dcn_fused(
    const unsigned short* __restrict__ xTbf, const float* __restrict__ off_buf,
    const unsigned short* __restrict__ W2, float* __restrict__ out) {
  __shared__ f32x2 slyx[128][9];   // (ly, lx)
  __shared__ u16x4 spos[128][9];   // corner pos (12b) | validity<<15
  __shared__ short ldsA[2][128 * 64];   // 32KB
  __shared__ short ldsB[2][256 * 64];   // 64KB

  const int tid = threadIdx.x;
  const int lane = tid & 63;
  const int wid = __builtin_amdgcn_readfirstlane(tid >> 6);
  const int m0 = xcd_swz256(blockIdx.x) * 128;
  const int b = m0 >> 12;
  const unsigned short* xb = xTbf + ((size_t)b << 20);

  // ---- phase 0: sampling params for 128 rows x 9 taps ----
  for (int idx = tid; idx < 128 * 9; idx += 512) {
    const int r = idx / 9, k = idx - (idx / 9) * 9;
    const int ky = k / 3, kx = k - ky * 3;
    const int pos = (m0 & 4095) + r;
    const int h = pos >> 6, w = pos & 63;
    const float offy = off_buf[(size_t)(m0 + r) * 18 + 2 * k];
    const float offx = off_buf[(size_t)(m0 + r) * 18 + 2 * k + 1];
    const float sy = offy + (float)(h - 1 + ky);
    const float sx = offx + (float)(w - 1 + kx);
    const float y0f = floorf(sy), x0f = floorf(sx);
    const int y0 = (int)y0f, x0 = (int)x0f;
    const int y1 = y0 + 1, x1 = x0 + 1;
    const unsigned vy0 = ((unsigned)y0 < 64u), vy1 = ((unsigned)y1 < 64u);
    const unsigned vx0 = ((unsigned)x0 < 64u), vx1 = ((unsigned)x1 < 64u);
    const int y0c = min(max(y0, 0), HW - 1), y1c = min(max(y1, 0), HW - 1);
    const int x0c = min(max(x0, 0), HW - 1), x1c = min(max(x1, 0), HW - 1);
    f32x2 lyx;
    lyx[0] = sy - y0f;
    lyx[1] = sx - x0f;
    u16x4 pp;
    pp[0] = (unsigned short)(((y0c << 6) + x0c) | ((vy0 & vx0) << 15));
    pp[1] = (unsigned short)(((y0c << 6) + x1c) | ((vy0 & vx1) << 15));
    pp[2] = (unsigned short)(((y1c << 6) + x0c) | ((vy1 & vx0) << 15));
    pp[3] = (unsigned short)(((y1c << 6) + x1c) | ((vy1 & vx1) << 15));
    slyx[r][k] = lyx;
    spos[r][k] = pp;
  }

  // ---- roles ----
  const int r = tid >> 2, q = tid & 3;  // sampling: row, 16-ch sixteenth
  const int dstA0 = r * 64 + (((2 * q) ^ (r & 7)) << 3);
  const int dstA1 = r * 64 + (((2 * q + 1) ^ (r & 7)) << 3);

  // B staging: 4 GLLs; dst lane-linear (idx*8 shorts), source pre-swizzled.
  const unsigned short* srcBp[4];
  int dstB[4];
#pragma unroll
  for (int g = 0; g < 4; ++g) {
    const int idx = g * 512 + tid;
    const int row = idx >> 3, c = idx & 7;
    srcBp[g] = W2 + (size_t)row * KDIM + ((c ^ (row & 7)) << 3);
    dstB[g] = idx * 8;
  }

  const int l15 = lane & 15, l4 = lane >> 4;
  const int wm = wid & 1, wn = wid >> 1;
  int offA[4][2], offB[4][2];
#pragma unroll
  for (int f = 0; f < 4; ++f) {
    const int rA = wm * 64 + f * 16 + l15;
    const int rB = wn * 64 + f * 16 + l15;
#pragma unroll
    for (int h = 0; h < 2; ++h) {
      offA[f][h] = rA * 64 + (((h * 4 + l4) ^ (rA & 7)) << 3);
      offB[f][h] = rB * 64 + (((h * 4 + l4) ^ (rB & 7)) << 3);
    }
  }

  const f32x4 z = {0.f, 0.f, 0.f, 0.f};
  f32x4 acc[4][4];
#pragma unroll
  for (int i = 0; i < 4; ++i)
#pragma unroll
    for (int j = 0; j < 4; ++j) acc[i][j] = z;

  __syncthreads();  // params visible

  // per-tap params
  f32x4 wv;
  int av[4];
  auto load_params = [&](int tap) {
    const f32x2 lyx = slyx[r][tap];
    const u16x4 pp = spos[r][tap];
    const float ly = lyx[0], lx = lyx[1];
#pragma unroll
    for (int e = 0; e < 4; ++e) av[e] = (int)(pp[e] & 0x0FFFu) << 8;
    wv[0] = (1.f - ly) * (1.f - lx) * (float)(pp[0] >> 15);
    wv[1] = (1.f - ly) * lx * (float)(pp[1] >> 15);
    wv[2] = ly * (1.f - lx) * (float)(pp[2] >> 15);
    wv[3] = ly * lx * (float)(pp[3] >> 15);
  };

  // gather regs: 16 channels = 2 u16x8 per corner
  u16x8 gc0[2], gc1[2], gc2[2], gc3[2];
  f32x4 gw;

  auto issue_gathers = [&](int t) {
    const int cb = ((t & 3) << 6) + q * 16;  // channel base within image row
#pragma unroll
    for (int h = 0; h < 2; ++h) {
      gc0[h] = *(const u16x8*)(xb + av[0] + cb + h * 8);
      gc1[h] = *(const u16x8*)(xb + av[1] + cb + h * 8);
      gc2[h] = *(const u16x8*)(xb + av[2] + cb + h * 8);
      gc3[h] = *(const u16x8*)(xb + av[3] + cb + h * 8);
    }
    gw = wv;
  };

  auto lerp_store = [&](int buf) {
    short* base = ldsA[buf];
#pragma unroll
    for (int h = 0; h < 2; ++h) {
      u32x4 wds;
#pragma unroll
      for (int e = 0; e < 4; ++e) {
        const float f0 = gw[0] * bf2f(gc0[h][2 * e]) + gw[1] * bf2f(gc1[h][2 * e]) +
                         gw[2] * bf2f(gc2[h][2 * e]) + gw[3] * bf2f(gc3[h][2 * e]);
        const float f1 = gw[0] * bf2f(gc0[h][2 * e + 1]) +
                         gw[1] * bf2f(gc1[h][2 * e + 1]) +
                         gw[2] * bf2f(gc2[h][2 * e + 1]) +
                         gw[3] * bf2f(gc3[h][2 * e + 1]);
        wds[e] = cvt_pk_bf16(f0, f1);
      }
      *(u32x4*)&base[h == 0 ? dstA0 : dstA1] = wds;
    }
  };

  // ---- prologue: tile 0 ----
  load_params(0);
  issue_gathers(0);
  lerp_store(0);
#pragma unroll
  for (int g = 0; g < 4; ++g) GLL16(srcBp[g], &ldsB[0][dstB[g]]);
  __syncthreads();

  // ---- main loop: 36 K-steps ----
  for (int t = 0; t < 36; ++t) {
    const int buf = t & 1;
    if (t < 35) {
      const int tn = t + 1;
#pragma unroll
      for (int g = 0; g < 4; ++g) GLL16(srcBp[g] + tn * 64, &ldsB[buf ^ 1][dstB[g]]);
      if ((tn & 3) == 0) load_params(tn >> 2);
      issue_gathers(tn);  // early issue (T14)
    }
#pragma unroll
    for (int h = 0; h < 2; ++h) {
      bf16x8 af[4], bfr[4];
#pragma unroll
      for (int f = 0; f < 4; ++f) {
        af[f] = *(const bf16x8*)&ldsA[buf][offA[f][h]];
        bfr[f] = *(const bf16x8*)&ldsB[buf][offB[f][h]];
      }
#pragma unroll
      for (int i = 0; i < 4; ++i)
#pragma unroll
        for (int j = 0; j < 4; ++j)
          acc[i][j] = __builtin_amdgcn_mfma_f32_16x16x32_bf16(af[i], bfr[j],
                                                              acc[i][j], 0, 0, 0);
    }
    if (t < 35) lerp_store(buf ^ 1);  // late write: gathers covered by MFMAs
    __syncthreads();
  }

  // ---- epilogue ----
#pragma unroll
  for (int i = 0; i < 4; ++i) {
    const int m = m0 + wm * 64 + i * 16 + l4 * 4;
    const int bb = m >> 12;
    const int pos = m & 4095;
#pragma unroll
    for (int j = 0; j < 4; ++j) {
      const int o = wn * 64 + j * 16 + l15;
      *(f32x4*)(out + (((size_t)bb * OCH + o) << 12) + pos) = acc[i][j];
    }
  }
}

extern "C" void kernel_launch(void* const* d_in, const int* in_sizes, int n_in,
                              void* d_out, int out_size, void* d_ws,
                              size_t ws_size, hipStream_t stream) {
  const float* x = (const float*)d_in[0];
  const float* w_off = (const float*)d_in[1];
  const float* b_off = (const float*)d_in[2];
  const float* w_dcn = (const float*)d_in[3];
  float* out = (float*)d_out;

  char* ws = (char*)d_ws;
  float* off_buf = (float*)(ws);                            //  2,359,296 B
  unsigned short* Wop = (unsigned short*)(ws + 2359296);    //    147,456 B
  unsigned short* zp = (unsigned short*)(ws + 2506752);     //      1,024 B
  unsigned short* W2 = (unsigned short*)(ws + 2507776);     //  1,179,648 B
  unsigned short* xTbf = (unsigned short*)(ws + 3687424);   // 16,777,216 B
  // total 20,464,640 B

  prep_xpose<<<4352, 256, 0, stream>>>(x, w_dcn, w_off, xTbf, W2, Wop, zp);
  offset_gemm<<<256, 512, 0, stream>>>(xTbf, Wop, zp, b_off, off_buf);
  dcn_fused<<<256, 512, 0, stream>>>(xTbf, off_buf, W2, out);
}